// Round 3
// baseline (496.397 us; speedup 1.0000x reference)
//
#include <hip/hip_runtime.h>
#include <hip/hip_bf16.h>

#define N_NODES 100000
#define N_EDGES 500000
#define EDIM 128
#define Z_BLOCKS 6250   // N_NODES*EDIM/8/256 exactly

using bf16x8 = __attribute__((ext_vector_type(8))) __bf16;
using f32x4  = __attribute__((ext_vector_type(4))) float;

// ---- prep: blocks [0,6250) convert z f32->bf16; blocks [6250,6266) convert W1
//      into MFMA B-fragment order.
// fragment (kt,nt): 64 lanes x 8 elems; lane holds B[k=kt*32+(l>>4)*8+i][n=nt*16+(l&15)]
__global__ void prep_kernel(const float* __restrict__ z, const float* __restrict__ W1,
                            __bf16* __restrict__ zb, __bf16* __restrict__ w1f) {
    int b = blockIdx.x;
    if (b < Z_BLOCKS) {
        int i = b * 256 + threadIdx.x;                   // 8 elems/thread
        const float4* p = (const float4*)z + (size_t)i * 2;
        float4 a = p[0], c = p[1];
        bf16x8 o;
        o[0] = (__bf16)a.x; o[1] = (__bf16)a.y; o[2] = (__bf16)a.z; o[3] = (__bf16)a.w;
        o[4] = (__bf16)c.x; o[5] = (__bf16)c.y; o[6] = (__bf16)c.z; o[7] = (__bf16)c.w;
        ((bf16x8*)zb)[i] = o;
    } else {
        int t = (b - Z_BLOCKS) * 256 + threadIdx.x;      // 0..4095
        int lane = t & 63, frag = t >> 6;
        int kt = frag >> 3, nt = frag & 7;
        int k0 = kt * 32 + (lane >> 4) * 8;
        int n  = nt * 16 + (lane & 15);
        bf16x8 o;
#pragma unroll
        for (int i = 0; i < 8; i++) o[i] = (__bf16)W1[(k0 + i) * 128 + n];
        ((bf16x8*)w1f)[t] = o;
    }
}

// ---- main: 512 threads = 8 waves, 64 edges/wave; W1 (64 KB) in LDS fragment-ordered.
// launch_bounds(512,4): 4 waves/EU -> 2 blocks/CU -> 16 waves/CU (50% occ).
__global__ __launch_bounds__(512, 4) void decode_kernel(
    const __bf16* __restrict__ zb, const __bf16* __restrict__ w1f,
    const int* __restrict__ ei, const float* __restrict__ b1,
    const float* __restrict__ W2, const float* __restrict__ b2,
    float* __restrict__ out)
{
    __shared__ __bf16 sW[64 * 512];  // 64 KB, fragment-ordered (conflict-free reads)
    {
        const uint4* src = (const uint4*)w1f;
        uint4* dst = (uint4*)sW;
#pragma unroll
        for (int i = 0; i < 8; i++)
            dst[threadIdx.x + 512 * i] = src[threadIdx.x + 512 * i];
    }
    __syncthreads();

    const int lane = threadIdx.x & 63;
    const int wave = threadIdx.x >> 6;
    const int l15 = lane & 15, l4 = lane >> 4;
    const long long ebase = (long long)blockIdx.x * 512 + wave * 64;

    // per-lane row pointers for the 4 M-tiles (lane group l15 owns edge row l15)
    const __bf16* aptr[4][2];
#pragma unroll
    for (int mt = 0; mt < 4; mt++) {
        long long e = ebase + mt * 16 + l15;
        if (e >= N_EDGES) e = N_EDGES - 1;          // clamp for tail (store predicated)
        int si = ei[e];
        int di = ei[N_EDGES + e];
        aptr[mt][0] = zb + (size_t)si * EDIM + l4 * 8;
        aptr[mt][1] = zb + (size_t)di * EDIM + l4 * 8;
    }

    const f32x4 zero = {0.f, 0.f, 0.f, 0.f};
    f32x4 acc[4][8];
#pragma unroll
    for (int mt = 0; mt < 4; mt++)
#pragma unroll
        for (int nt = 0; nt < 8; nt++) acc[mt][nt] = zero;

#pragma unroll
    for (int kt = 0; kt < 8; kt++) {
        bf16x8 bfr[8];
#pragma unroll
        for (int nt = 0; nt < 8; nt++)
            bfr[nt] = *(const bf16x8*)&sW[(kt * 8 + nt) * 512 + lane * 8];
        const int half = kt >> 2;          // 0: src embedding, 1: dst embedding
        const int ko   = (kt & 3) * 32;    // k offset within that embedding
#pragma unroll
        for (int mt = 0; mt < 4; mt++) {
            bf16x8 a = *(const bf16x8*)(aptr[mt][half] + ko);
#pragma unroll
            for (int nt = 0; nt < 8; nt++)
                acc[mt][nt] = __builtin_amdgcn_mfma_f32_16x16x32_bf16(a, bfr[nt], acc[mt][nt], 0, 0, 0);
        }
    }

    // epilogue: h = relu(acc + b1); out = h . W2 + b2
    float b1v[8], w2v[8];
#pragma unroll
    for (int nt = 0; nt < 8; nt++) {
        int c = nt * 16 + l15;
        b1v[nt] = b1[c];
        w2v[nt] = W2[c];
    }
    const float bias2 = b2[0];

#pragma unroll
    for (int mt = 0; mt < 4; mt++) {
#pragma unroll
        for (int j = 0; j < 4; j++) {
            float p = 0.f;
#pragma unroll
            for (int nt = 0; nt < 8; nt++)
                p += fmaxf(acc[mt][nt][j] + b1v[nt], 0.f) * w2v[nt];
            p += __shfl_xor(p, 1, 64);
            p += __shfl_xor(p, 2, 64);
            p += __shfl_xor(p, 4, 64);
            p += __shfl_xor(p, 8, 64);
            long long e = ebase + mt * 16 + l4 * 4 + j;
            if (l15 == 0 && e < N_EDGES) out[e] = p + bias2;
        }
    }
}

extern "C" void kernel_launch(void* const* d_in, const int* in_sizes, int n_in,
                              void* d_out, int out_size, void* d_ws, size_t ws_size,
                              hipStream_t stream) {
    const float* z  = (const float*)d_in[0];
    const int*   ei = (const int*)d_in[1];   // [2, N_EDGES] int32
    const float* W1 = (const float*)d_in[2];
    const float* b1 = (const float*)d_in[3];
    const float* W2 = (const float*)d_in[4];
    const float* b2 = (const float*)d_in[5];
    float* out = (float*)d_out;

    __bf16* zb  = (__bf16*)d_ws;                                        // 25.6 MB
    __bf16* w1f = (__bf16*)((char*)d_ws + (size_t)N_NODES * EDIM * 2);  // 64 KB

    prep_kernel<<<Z_BLOCKS + 16, 256, 0, stream>>>(z, W1, zb, w1f);
    decode_kernel<<<(N_EDGES + 511) / 512, 512, 0, stream>>>(zb, w1f, ei, b1, W2, b2, out);
}

// Round 5
// 154.358 us; speedup vs baseline: 3.2159x; 3.2159x over previous
//
#include <hip/hip_runtime.h>
#include <hip/hip_bf16.h>

#define N_NODES 100000
#define N_EDGES 500000

using bf16x8 = __attribute__((ext_vector_type(8))) __bf16;
using f32x4  = __attribute__((ext_vector_type(4))) float;

// ws layout: [0,64KB) w1f = W' [128,256] bf16 in MFMA B-fragment order;
//            [64KB, +51.2MB) C = [N_NODES][256] bf16  (cols 0..127 = u, 128..255 = v)
//
// h = relu(src@W1a + dst@W1b + b1) ; W' = [W1a | W1b], so
// C[node][n] = sum_k z[node][k] * W'[k][n]

// ---- kernel 1: W1 f32 -> W' bf16 fragment-ordered (16 blocks x 256) ----
// frag = kq*16 + nt ; lane holds W'[k = kq*32+(l>>4)*8+i][n = nt*16+(l&15)]
__global__ void cvt_w1f_kernel(const float* __restrict__ W1, __bf16* __restrict__ w1f) {
    int t = blockIdx.x * 256 + threadIdx.x;  // 0..4095
    int lane = t & 63, frag = t >> 6;
    int kq = frag >> 4, nt = frag & 15;
    int k0 = kq * 32 + (lane >> 4) * 8;
    int n  = nt * 16 + (lane & 15);
    bf16x8 o;
#pragma unroll
    for (int i = 0; i < 8; i++) {
        int k = k0 + i;
        float w = (n < 128) ? W1[k * 128 + n] : W1[(k + 128) * 128 + (n - 128)];
        o[i] = (__bf16)w;
    }
    ((bf16x8*)w1f)[t] = o;
}

// ---- kernel 2: node GEMM  C = z @ W'  (block: 128 rows x 256 cols, 4 waves 2x2) ----
__global__ __launch_bounds__(256, 2) void node_gemm_kernel(
    const float* __restrict__ z, const __bf16* __restrict__ w1f,
    __bf16* __restrict__ C)
{
    __shared__ __bf16 sW[64 * 512];  // 64 KB fragment-ordered, conflict-free reads
    {
        const uint4* src = (const uint4*)w1f;
        uint4* dst = (uint4*)sW;
#pragma unroll
        for (int i = 0; i < 16; i++)
            dst[threadIdx.x + 256 * i] = src[threadIdx.x + 256 * i];
    }
    __syncthreads();

    const int lane = threadIdx.x & 63;
    const int wave = threadIdx.x >> 6;
    const int l15 = lane & 15, l4 = lane >> 4;
    const int wr = wave >> 1, wc = wave & 1;       // 2x2 wave grid
    const int rowbase = blockIdx.x * 128 + wr * 64;

    const float* arow[4];
#pragma unroll
    for (int mt = 0; mt < 4; mt++) {
        int r = rowbase + mt * 16 + l15;
        if (r >= N_NODES) r = N_NODES - 1;         // tail clamp, store predicated
        arow[mt] = z + (size_t)r * 128 + l4 * 8;
    }

    const f32x4 zero = {0.f, 0.f, 0.f, 0.f};
    f32x4 acc[4][8];
#pragma unroll
    for (int mt = 0; mt < 4; mt++)
#pragma unroll
        for (int nt = 0; nt < 8; nt++) acc[mt][nt] = zero;

#pragma unroll
    for (int kq = 0; kq < 4; kq++) {
        bf16x8 bfr[8];
#pragma unroll
        for (int nt = 0; nt < 8; nt++) {
            int fid = kq * 16 + wc * 8 + nt;
            bfr[nt] = *(const bf16x8*)&sW[fid * 512 + lane * 8];
        }
#pragma unroll
        for (int mt = 0; mt < 4; mt++) {
            const float4* p = (const float4*)(arow[mt] + kq * 32);
            float4 x0 = p[0], x1 = p[1];
            bf16x8 a;
            a[0] = (__bf16)x0.x; a[1] = (__bf16)x0.y; a[2] = (__bf16)x0.z; a[3] = (__bf16)x0.w;
            a[4] = (__bf16)x1.x; a[5] = (__bf16)x1.y; a[6] = (__bf16)x1.z; a[7] = (__bf16)x1.w;
#pragma unroll
            for (int nt = 0; nt < 8; nt++)
                acc[mt][nt] = __builtin_amdgcn_mfma_f32_16x16x32_bf16(a, bfr[nt], acc[mt][nt], 0, 0, 0);
        }
    }

    // store: C[r][c], r = rowbase+mt*16+l4*4+j, c = wc*128 + nt*16 + l15
#pragma unroll
    for (int mt = 0; mt < 4; mt++) {
#pragma unroll
        for (int j = 0; j < 4; j++) {
            int r = rowbase + mt * 16 + l4 * 4 + j;
            if (r < N_NODES) {
#pragma unroll
                for (int nt = 0; nt < 8; nt++)
                    C[(size_t)r * 256 + wc * 128 + nt * 16 + l15] = (__bf16)acc[mt][nt][j];
            }
        }
    }
}

// ---- kernel 3: edge gather + fused epilogue ----
// lane = g*16 + sub : g = edge-in-quad (4 edges/wave-step), sub = channel group (8 ch)
__global__ __launch_bounds__(256, 4) void edge_kernel(
    const __bf16* __restrict__ C, const int* __restrict__ ei,
    const float* __restrict__ b1, const float* __restrict__ W2,
    const float* __restrict__ b2, float* __restrict__ out)
{
    const int lane = threadIdx.x & 63;
    const int wave = threadIdx.x >> 6;
    const int g = lane >> 4, sub = lane & 15;

    const float4* b1p = (const float4*)(b1 + sub * 8);
    const float4* w2p = (const float4*)(W2 + sub * 8);
    float4 bb0 = b1p[0], bb1 = b1p[1];
    float4 ww0 = w2p[0], ww1 = w2p[1];
    float b1v[8] = {bb0.x, bb0.y, bb0.z, bb0.w, bb1.x, bb1.y, bb1.z, bb1.w};
    float w2v[8] = {ww0.x, ww0.y, ww0.z, ww0.w, ww1.x, ww1.y, ww1.z, ww1.w};
    const float bias2 = b2[0];

    const int wid = blockIdx.x * 4 + wave;
    const int nw  = gridDim.x * 4;

    // 16 edges per wave-iteration (4 quads), N_EDGES % 16 == 0
    for (long long eb = (long long)wid * 16; eb < N_EDGES; eb += (long long)nw * 16) {
        bf16x8 cu[4], cv[4];
        long long e[4];
#pragma unroll
        for (int q = 0; q < 4; q++) {
            e[q] = eb + q * 4 + g;
            int is = ei[e[q]];
            int id = ei[N_EDGES + e[q]];
            cu[q] = *(const bf16x8*)(C + (size_t)is * 256 + sub * 8);
            cv[q] = *(const bf16x8*)(C + (size_t)id * 256 + 128 + sub * 8);
        }
#pragma unroll
        for (int q = 0; q < 4; q++) {
            float p = 0.f;
#pragma unroll
            for (int i = 0; i < 8; i++) {
                float h = (float)cu[q][i] + (float)cv[q][i] + b1v[i];
                p += fmaxf(h, 0.f) * w2v[i];
            }
            p += __shfl_xor(p, 1, 64);
            p += __shfl_xor(p, 2, 64);
            p += __shfl_xor(p, 4, 64);
            p += __shfl_xor(p, 8, 64);
            if (sub == 0) out[e[q]] = p + bias2;
        }
    }
}

extern "C" void kernel_launch(void* const* d_in, const int* in_sizes, int n_in,
                              void* d_out, int out_size, void* d_ws, size_t ws_size,
                              hipStream_t stream) {
    const float* z  = (const float*)d_in[0];
    const int*   ei = (const int*)d_in[1];   // [2, N_EDGES] int32
    const float* W1 = (const float*)d_in[2];
    const float* b1 = (const float*)d_in[3];
    const float* W2 = (const float*)d_in[4];
    const float* b2 = (const float*)d_in[5];
    float* out = (float*)d_out;

    __bf16* w1f = (__bf16*)d_ws;                           // 64 KB
    __bf16* Cbuf = (__bf16*)((char*)d_ws + 65536);         // 51.2 MB

    cvt_w1f_kernel<<<16, 256, 0, stream>>>(W1, w1f);
    node_gemm_kernel<<<(N_NODES + 127) / 128, 256, 0, stream>>>(z, w1f, Cbuf);
    edge_kernel<<<2048, 256, 0, stream>>>(Cbuf, ei, b1, W2, b2, out);
}

// Round 6
// 149.687 us; speedup vs baseline: 3.3162x; 1.0312x over previous
//
#include <hip/hip_runtime.h>
#include <hip/hip_bf16.h>

#define N_NODES 100000
#define N_EDGES 500000

using bf16x8 = __attribute__((ext_vector_type(8))) __bf16;
using f32x4  = __attribute__((ext_vector_type(4))) float;

// ws layout: [0,64KB) w1f = W' [128,256] bf16, MFMA B-fragment order;
//            [64KB, +51.2MB) C = [N_NODES][256] bf16, PERMUTED per 128-col half:
//            C[r][h*128 + (c&15)*8 + (c>>4)] = (z[r] @ W'_h)[c]
// h = relu(src@W1a + dst@W1b + b1); W' = [W1a | W1b]

// ---- kernel 1: W1 f32 -> W' bf16 fragment-ordered ----
// frag = kq*16 + c16 ; lane holds W'[k = kq*32+(l>>4)*8+i][n = c16*16+(l&15)]
__global__ void cvt_w1f_kernel(const float* __restrict__ W1, __bf16* __restrict__ w1f) {
    int t = blockIdx.x * 256 + threadIdx.x;  // 0..4095
    int lane = t & 63, frag = t >> 6;
    int kq = frag >> 4, c16 = frag & 15;
    int k0 = kq * 32 + (lane >> 4) * 8;
    int n  = c16 * 16 + (lane & 15);
    bf16x8 o;
#pragma unroll
    for (int i = 0; i < 8; i++) {
        int k = k0 + i;
        float w = (n < 128) ? W1[k * 128 + n] : W1[(k + 128) * 128 + (n - 128)];
        o[i] = (__bf16)w;
    }
    ((bf16x8*)w1f)[t] = o;
}

// ---- kernel 2: node GEMM, block = 256 rows x 128 cols (col-half = blockIdx.y) ----
// 4 waves x 64 rows each; LDS = 32 KB (this half's 32 fragments) -> VGPR-limited occ.
__global__ __launch_bounds__(256, 2) void node_gemm_kernel(
    const float* __restrict__ z, const __bf16* __restrict__ w1f,
    __bf16* __restrict__ C)
{
    __shared__ __bf16 sW[32 * 512];  // 32 KB
    const int h = blockIdx.y;
    {
        const uint4* src = (const uint4*)w1f;
        uint4* dst = (uint4*)sW;
#pragma unroll
        for (int i = 0; i < 8; i++) {
            int u = threadIdx.x + 256 * i;        // 0..2047 uint4 slots
            int s = u >> 6, w = u & 63;           // LDS frag slot s = kq*8+nt
            int kq = s >> 3, nt = s & 7;
            dst[u] = src[(kq * 16 + h * 8 + nt) * 64 + w];
        }
    }
    __syncthreads();

    const int lane = threadIdx.x & 63;
    const int wave = threadIdx.x >> 6;
    const int l15 = lane & 15, l4 = lane >> 4;
    const int rowbase = blockIdx.x * 256 + wave * 64;

    const float* arow[4];
#pragma unroll
    for (int mt = 0; mt < 4; mt++) {
        int r = rowbase + mt * 16 + l15;
        if (r >= N_NODES) r = N_NODES - 1;        // tail clamp, store predicated
        arow[mt] = z + (size_t)r * 128 + l4 * 8;
    }

    const f32x4 zero = {0.f, 0.f, 0.f, 0.f};
    f32x4 acc[4][8];
#pragma unroll
    for (int mt = 0; mt < 4; mt++)
#pragma unroll
        for (int nt = 0; nt < 8; nt++) acc[mt][nt] = zero;

#pragma unroll
    for (int kq = 0; kq < 4; kq++) {
        bf16x8 bfr[8];
#pragma unroll
        for (int nt = 0; nt < 8; nt++)
            bfr[nt] = *(const bf16x8*)&sW[(kq * 8 + nt) * 512 + lane * 8];
#pragma unroll
        for (int mt = 0; mt < 4; mt++) {
            const float4* p = (const float4*)(arow[mt] + kq * 32);
            float4 x0 = p[0], x1 = p[1];
            bf16x8 a;
            a[0] = (__bf16)x0.x; a[1] = (__bf16)x0.y; a[2] = (__bf16)x0.z; a[3] = (__bf16)x0.w;
            a[4] = (__bf16)x1.x; a[5] = (__bf16)x1.y; a[6] = (__bf16)x1.z; a[7] = (__bf16)x1.w;
#pragma unroll
            for (int nt = 0; nt < 8; nt++)
                acc[mt][nt] = __builtin_amdgcn_mfma_f32_16x16x32_bf16(a, bfr[nt], acc[mt][nt], 0, 0, 0);
        }
    }

    // permuted store: lane packs its 8 nt-values of row r -> one bf16x8
    // C[r*256 + h*128 + l15*8 + nt] = acc[mt][nt][j]   (c' = l15*8 + nt)
#pragma unroll
    for (int mt = 0; mt < 4; mt++) {
#pragma unroll
        for (int j = 0; j < 4; j++) {
            int r = rowbase + mt * 16 + l4 * 4 + j;
            if (r < N_NODES) {
                bf16x8 o;
#pragma unroll
                for (int nt = 0; nt < 8; nt++) o[nt] = (__bf16)acc[mt][nt][j];
                *(bf16x8*)(C + (size_t)r * 256 + h * 128 + l15 * 8) = o;
            }
        }
    }
}

// ---- kernel 3: edge gather + fused epilogue (permuted-channel aware) ----
// lane = g*16 + sub ; lane sub holds channels {i*16+sub : i=0..7} of each half
__global__ __launch_bounds__(256, 6) void edge_kernel(
    const __bf16* __restrict__ C, const int* __restrict__ ei,
    const float* __restrict__ b1, const float* __restrict__ W2,
    const float* __restrict__ b2, float* __restrict__ out)
{
    const int lane = threadIdx.x & 63;
    const int wave = threadIdx.x >> 6;
    const int g = lane >> 4, sub = lane & 15;

    float b1v[8], w2v[8];
#pragma unroll
    for (int i = 0; i < 8; i++) {
        b1v[i] = b1[i * 16 + sub];
        w2v[i] = W2[i * 16 + sub];
    }
    const float bias2 = b2[0];

    const int wid = blockIdx.x * 4 + wave;
    const int nw  = gridDim.x * 4;

    // 16 edges per wave-iteration (4 quads)
    for (int eb = wid * 16; eb < N_EDGES; eb += nw * 16) {
        bf16x8 cu[4], cv[4];
        int e[4];
#pragma unroll
        for (int q = 0; q < 4; q++) {
            e[q] = eb + q * 4 + g;
            int is = ei[e[q]];
            int id = ei[N_EDGES + e[q]];
            cu[q] = *(const bf16x8*)(C + (size_t)is * 256 + sub * 8);
            cv[q] = *(const bf16x8*)(C + (size_t)id * 256 + 128 + sub * 8);
        }
#pragma unroll
        for (int q = 0; q < 4; q++) {
            float p = 0.f;
#pragma unroll
            for (int i = 0; i < 8; i++) {
                float hc = (float)cu[q][i] + (float)cv[q][i] + b1v[i];
                p += fmaxf(hc, 0.f) * w2v[i];
            }
            p += __shfl_xor(p, 1, 64);
            p += __shfl_xor(p, 2, 64);
            p += __shfl_xor(p, 4, 64);
            p += __shfl_xor(p, 8, 64);
            if (sub == 0) out[e[q]] = p + bias2;
        }
    }
}

extern "C" void kernel_launch(void* const* d_in, const int* in_sizes, int n_in,
                              void* d_out, int out_size, void* d_ws, size_t ws_size,
                              hipStream_t stream) {
    const float* z  = (const float*)d_in[0];
    const int*   ei = (const int*)d_in[1];   // [2, N_EDGES] int32
    const float* W1 = (const float*)d_in[2];
    const float* b1 = (const float*)d_in[3];
    const float* W2 = (const float*)d_in[4];
    const float* b2 = (const float*)d_in[5];
    float* out = (float*)d_out;

    __bf16* w1f  = (__bf16*)d_ws;                          // 64 KB
    __bf16* Cbuf = (__bf16*)((char*)d_ws + 65536);         // 51.2 MB

    cvt_w1f_kernel<<<16, 256, 0, stream>>>(W1, w1f);
    dim3 ggrid((N_NODES + 255) / 256, 2);
    node_gemm_kernel<<<ggrid, 256, 0, stream>>>(z, w1f, Cbuf);
    edge_kernel<<<2048, 256, 0, stream>>>(Cbuf, ei, b1, W2, b2, out);
}